// Round 17
// baseline (1624.249 us; speedup 1.0000x reference)
//
#include <hip/hip_runtime.h>
#include <math.h>

#define NROWS 131072
#define DIMD  128
#define KCB   1024
#define NLEV  4
#define RB    32                 // rows per block (1 wave)
#define EPS_GAP 5.0e-5f          // > 2*delta_max (grid 1.5e-5 + split/chain ~6e-6)

typedef __attribute__((ext_vector_type(8))) short short8;
typedef __attribute__((ext_vector_type(4))) float f32x4;

// d_ws layout (~2.1 MB): [0,16) lossAcc, [16,16400) e2g[4096], hiT/loT frag tables
#define WS_E2G   16
#define WS_HIT   16400
#define WS_LOT   (16400 + 1048576)

// numpy pairwise sumsq (AVX512 path) — validated R3..R16. Do not reassociate.
__device__ __forceinline__ float np_sumsq128(const float* __restrict__ p) {
    float q[16];
    #pragma unroll
    for (int lane = 0; lane < 16; ++lane) {
        float c[8];
        #pragma unroll
        for (int j = 0; j < 8; ++j) { float v = p[16 * j + lane]; c[j] = v * v; }
        float s01 = c[0] + c[1], s23 = c[2] + c[3];
        float s45 = c[4] + c[5], s67 = c[6] + c[7];
        q[lane] = (s01 + s23) + (s45 + s67);
    }
    float t[8];
    #pragma unroll
    for (int j = 0; j < 8; ++j) t[j] = q[j] + q[j + 8];
    float u[4];
    #pragma unroll
    for (int j = 0; j < 4; ++j) u[j] = t[j] + t[j + 4];
    float w0 = u[0] + u[2], w1 = u[1] + u[3];
    return w0 + w1;
}

__device__ __forceinline__ short8 as_short8(uint4 u) {
    short8 v; __builtin_memcpy(&v, &u, 16); return v;
}

// launch_bounds(64,1): allow up to 512 VGPR — LDS already caps residency at
// 2 waves/SIMD, so the allocator must NOT spill to protect 128-reg occupancy
// (R16's 527MB scratch-write signature).
__global__ __launch_bounds__(64, 1)
void rvq_main(const float* __restrict__ x, const float* __restrict__ cb,
              float* __restrict__ out, const float* __restrict__ e2g,
              const uint4* __restrict__ hiT, const uint4* __restrict__ loT,
              double* __restrict__ lossAcc)
{
    __shared__ float rS[RB * 132];                 // f32 residual chain
    __shared__ unsigned long long bestS[RB];
    __shared__ float A_S[RB];
    __shared__ int   kminS[RB], k2S[RB];
    __shared__ float devS[RB], swS[RB];
    __shared__ float commitS[RB], usageS[RB];
    __shared__ int   pairList[RB], fullList[RB];
    __shared__ int   pairCnt, fullCnt;

    const int tid = threadIdx.x;                   // 0..63 (one wave)
    const int li  = tid & 15;
    const int lg  = tid >> 4;
    const int rowBase = blockIdx.x * RB;
    const int cgOff = (int)(blockIdx.x & 63);      // per-block sweep stagger

    float4* rS4 = (float4*)rS;
    const float4* x4 = (const float4*)x;
    float4* out4 = (float4*)out;

    #pragma unroll
    for (int i = 0; i < 8; ++i) {
        int row = 8 * lg + i;
        size_t n = (size_t)rowBase + row;
        rS4[row * 33 + 2 * li]     = x4[n * 32 + 2 * li];
        rS4[row * 33 + 2 * li + 1] = x4[n * 32 + 2 * li + 1];
    }
    if (tid < RB) { commitS[tid] = 0.0f; usageS[tid] = 0.0f; }

    for (int lev = 0; lev < NLEV; ++lev) {
        __syncthreads();
        if (tid < RB) {
            A_S[tid]  = np_sumsq128(rS + tid * 132);
            bestS[tid] = ~0ULL;
        }
        if (tid == 0) { pairCnt = 0; fullCnt = 0; }

        const float* cbL  = cb  + (size_t)lev * KCB * DIMD;
        const float* e2gL = e2g + (size_t)lev * KCB;
        const uint4* hT = hiT + (size_t)lev * 16384;
        const uint4* lT = loT + (size_t)lev * 16384;

        // A fragments (bf16 hi/lo of 32 rows)
        short8 aH[2][4], aL[2][4];
        #pragma unroll
        for (int t = 0; t < 2; ++t) {
            int arow = 16 * t + li;
            #pragma unroll
            for (int ks = 0; ks < 4; ++ks) {
                float4 p = rS4[arow * 33 + 8 * ks + 2 * lg];
                float4 q = rS4[arow * 33 + 8 * ks + 2 * lg + 1];
                uint4 uh, ul;
                float pv[8] = {p.x, p.y, p.z, p.w, q.x, q.y, q.z, q.w};
                unsigned hb[8]; float lv[8];
                #pragma unroll
                for (int e = 0; e < 8; ++e) {
                    unsigned b = __float_as_uint(pv[e]);
                    hb[e] = b & 0xFFFF0000u;
                    lv[e] = pv[e] - __uint_as_float(hb[e]);
                }
                uh.x = (hb[0] >> 16) | hb[1]; uh.y = (hb[2] >> 16) | hb[3];
                uh.z = (hb[4] >> 16) | hb[5]; uh.w = (hb[6] >> 16) | hb[7];
                ul.x = (__float_as_uint(lv[0]) >> 16) | (__float_as_uint(lv[1]) & 0xFFFF0000u);
                ul.y = (__float_as_uint(lv[2]) >> 16) | (__float_as_uint(lv[3]) & 0xFFFF0000u);
                ul.z = (__float_as_uint(lv[4]) >> 16) | (__float_as_uint(lv[5]) & 0xFFFF0000u);
                ul.w = (__float_as_uint(lv[6]) >> 16) | (__float_as_uint(lv[7]) & 0xFFFF0000u);
                aH[t][ks] = as_short8(uh);
                aL[t][ks] = as_short8(ul);
            }
        }

        // top-3 values + top-2 indices per row-slot
        float m1[8], m2[8], m3[8], dev[8], swv[8];
        int   k1[8], k2[8];
        #pragma unroll
        for (int s = 0; s < 8; ++s) {
            m1[s] = -__builtin_inff(); m2[s] = -__builtin_inff(); m3[s] = -__builtin_inff();
            k1[s] = 0; k2[s] = 0; dev[s] = 0.f; swv[s] = 0.f;
        }

        // per-cg compute; Cc pre-fetched by caller (no load→MFMA-init stall).
        // Cross terms merged: accM = mfma(aL,bH, mfma(aH,bL, accM)) — 4 chains.
        auto compute_cg = [&](const uint4 (&hf)[4], const uint4 (&lf)[4],
                              int cgPhys, float Cc) {
            short8 bH[4], bL[4];
            #pragma unroll
            for (int ks = 0; ks < 4; ++ks) { bH[ks] = as_short8(hf[ks]); bL[ks] = as_short8(lf[ks]); }
            f32x4 accH0 = {-Cc,-Cc,-Cc,-Cc}, accH1 = {-Cc,-Cc,-Cc,-Cc};
            f32x4 accM0 = {0.f,0.f,0.f,0.f}, accM1 = {0.f,0.f,0.f,0.f};
            #pragma unroll
            for (int ks = 0; ks < 4; ++ks) {       // 4 independent chains
                accH0 = __builtin_amdgcn_mfma_f32_16x16x32_bf16(aH[0][ks], bH[ks], accH0, 0, 0, 0);
                accH1 = __builtin_amdgcn_mfma_f32_16x16x32_bf16(aH[1][ks], bH[ks], accH1, 0, 0, 0);
                accM0 = __builtin_amdgcn_mfma_f32_16x16x32_bf16(aH[0][ks], bL[ks], accM0, 0, 0, 0);
                accM1 = __builtin_amdgcn_mfma_f32_16x16x32_bf16(aH[1][ks], bL[ks], accM1, 0, 0, 0);
                accM0 = __builtin_amdgcn_mfma_f32_16x16x32_bf16(aL[0][ks], bH[ks], accM0, 0, 0, 0);
                accM1 = __builtin_amdgcn_mfma_f32_16x16x32_bf16(aL[1][ks], bH[ks], accM1, 0, 0, 0);
            }
            const int colg = cgPhys * 16 + li;
            #pragma unroll
            for (int t = 0; t < 2; ++t) {
                #pragma unroll
                for (int r = 0; r < 4; ++r) {
                    const int s = 4 * t + r;
                    float sv = t ? (accH1[r] + accM1[r]) : (accH0[r] + accM0[r]);
                    bool gt1 = sv > m1[s];
                    k2[s] = gt1 ? k1[s] : ((sv > m2[s]) ? colg : k2[s]);
                    k1[s] = gt1 ? colg : k1[s];
                    m3[s] = __builtin_amdgcn_fmed3f(sv, m2[s], m3[s]);   // new 3rd
                    m2[s] = __builtin_amdgcn_fmed3f(sv, m1[s], m2[s]);   // new 2nd
                    m1[s] = fmaxf(sv, m1[s]);
                    float e = __expf(sv);                     // |sv|<~0.35
                    dev[s] += (e - 1.0f);                     // Sterbenz-exact
                    swv[s]  = fmaf(sv, e, swv[s]);
                }
            }
        };

        // sweep 64 staggered col-groups; 2-deep reg double-buffer + Cc prefetch
        uint4 h0[4], l0[4], h1[4], l1[4];
        float c0, c1;
        {
            const int p0 = cgOff;
            #pragma unroll
            for (int ks = 0; ks < 4; ++ks) {
                h0[ks] = hT[(size_t)p0 * 256 + ks * 64 + tid];
                l0[ks] = lT[(size_t)p0 * 256 + ks * 64 + tid];
            }
            c0 = e2gL[p0 * 16 + li];
        }
        for (int g = 0; g < 64; g += 2) {
            const int p1 = (g + 1 + cgOff) & 63;
            #pragma unroll
            for (int ks = 0; ks < 4; ++ks) {
                h1[ks] = hT[(size_t)p1 * 256 + ks * 64 + tid];
                l1[ks] = lT[(size_t)p1 * 256 + ks * 64 + tid];
            }
            c1 = e2gL[p1 * 16 + li];
            compute_cg(h0, l0, (g + cgOff) & 63, c0);
            if (g + 2 < 64) {
                const int p2 = (g + 2 + cgOff) & 63;
                #pragma unroll
                for (int ks = 0; ks < 4; ++ks) {
                    h0[ks] = hT[(size_t)p2 * 256 + ks * 64 + tid];
                    l0[ks] = lT[(size_t)p2 * 256 + ks * 64 + tid];
                }
                c0 = e2gL[p2 * 16 + li];
            }
            compute_cg(h1, l1, p1, c1);
        }

        // merge sorted triples (+indices) across the 16 lanes sharing rows
        #pragma unroll
        for (int s = 0; s < 8; ++s) {
            #pragma unroll
            for (int m = 8; m >= 1; m >>= 1) {
                float b1 = __shfl_xor(m1[s], m), b2 = __shfl_xor(m2[s], m), b3 = __shfl_xor(m3[s], m);
                int  bk1 = __shfl_xor(k1[s], m), bk2 = __shfl_xor(k2[s], m);
                float a1 = m1[s], a2 = m2[s], a3 = m3[s];
                int  ak1 = k1[s], ak2 = k2[s];
                float n1, n2, n3; int nk1, nk2;
                if (a1 > b1) {
                    n1 = a1; nk1 = ak1;
                    if (a2 > b1)      { n2 = a2; nk2 = ak2; n3 = fmaxf(a3, b1); }
                    else if (a2 < b1) { n2 = b1; nk2 = bk1; n3 = fmaxf(a2, b2); }
                    else              { n2 = a2; nk2 = min(ak2, bk1); n3 = a2; }
                } else if (a1 < b1) {
                    n1 = b1; nk1 = bk1;
                    if (b2 > a1)      { n2 = b2; nk2 = bk2; n3 = fmaxf(b3, a1); }
                    else if (b2 < a1) { n2 = a1; nk2 = ak1; n3 = fmaxf(b2, a2); }
                    else              { n2 = b2; nk2 = min(bk2, ak1); n3 = b2; }
                } else {               // value tie at top: both indices kept
                    n1 = a1; nk1 = min(ak1, bk1);
                    n2 = a1; nk2 = (ak1 < bk1) ? bk1 : ak1;
                    n3 = fmaxf(a2, b2);
                }
                m1[s] = n1; m2[s] = n2; m3[s] = n3; k1[s] = nk1; k2[s] = nk2;
                dev[s] += __shfl_xor(dev[s], m);
                swv[s] += __shfl_xor(swv[s], m);
            }
        }

        // owners classify: accept / pair-check / full-scan
        if (li == 0) {
            #pragma unroll
            for (int t = 0; t < 2; ++t)
                #pragma unroll
                for (int r = 0; r < 4; ++r) {
                    const int s = 4 * t + r;
                    const int row = 16 * t + 4 * lg + r;
                    kminS[row] = k1[s];
                    k2S[row]   = k2[s];
                    devS[row]  = dev[s];
                    swS[row]   = swv[s];
                    if (!(m1[s] - m2[s] > EPS_GAP)) {
                        if (m1[s] - m3[s] > EPS_GAP)
                            pairList[atomicAdd(&pairCnt, 1)] = row;   // only k1,k2 contend
                        else
                            fullList[atomicAdd(&fullCnt, 1)] = row;   // ultra-rare
                    }
                }
        }
        __syncthreads();

        // pair rows: exact fp32-replica d32 for k1 (lanes<32) and k2 (lanes>=32)
        const int np = pairCnt;
        for (int h = 0; h < np; ++h) {
            const int row = pairList[h];
            const int myk = (tid < 32) ? kminS[row] : k2S[row];
            const float4* rr4 = (const float4*)(rS + row * 132);
            const float4* ep4 = (const float4*)(cbL + (size_t)myk * DIMD);
            float b = 0.f;
            #pragma unroll 8
            for (int c4 = 0; c4 < 32; ++c4) {      // sequential ascending-d FMA
                float4 rv = rr4[c4], ev = ep4[c4];
                b = fmaf(rv.x, ev.x, b);
                b = fmaf(rv.y, ev.y, b);
                b = fmaf(rv.z, ev.z, b);
                b = fmaf(rv.w, ev.w, b);
            }
            float m2b = 2.0f * b;
            float t1  = A_S[row] - m2b;
            float d32 = t1 + e2gL[myk];
            unsigned long long pk =
                ((unsigned long long)__float_as_uint(d32) << 32) | (unsigned)myk;
            unsigned long long o = __shfl_xor(pk, 32);
            if (o < pk) pk = o;
            if (tid == 0) bestS[row] = pk;
        }

        // full-scan rows (P ~ 3e-5): exact replica over all 1024 k
        const int nf = fullCnt;
        for (int h = 0; h < nf; ++h) {
            const int row = fullList[h];
            const float4* rrow4 = (const float4*)(rS + row * 132);
            const float Ar = A_S[row];
            unsigned long long best = ~0ULL;
            for (int kk = tid; kk < KCB; kk += 64) {
                const float4* ep4 = (const float4*)(cbL + (size_t)kk * DIMD);
                float b = 0.f;
                #pragma unroll 8
                for (int c4 = 0; c4 < 32; ++c4) {
                    float4 ev = ep4[c4];
                    float4 rv = rrow4[c4];
                    b = fmaf(rv.x, ev.x, b);
                    b = fmaf(rv.y, ev.y, b);
                    b = fmaf(rv.z, ev.z, b);
                    b = fmaf(rv.w, ev.w, b);
                }
                float m2b = 2.0f * b;
                float t1  = Ar - m2b;
                float d32 = t1 + e2gL[kk];
                unsigned long long pk =
                    ((unsigned long long)__float_as_uint(d32) << 32) | (unsigned)kk;
                if (pk < best) best = pk;
            }
            #pragma unroll
            for (int m = 32; m >= 1; m >>= 1) {
                unsigned long long o = __shfl_xor(best, m);
                if (o < best) best = o;
            }
            if (tid == 0) bestS[row] = best;
        }
        __syncthreads();

        // epilogue (R3/R6/R14 validated): residual chain, codes, losses, out
        #pragma unroll
        for (int i = 0; i < 8; ++i) {
            const int row = 8 * lg + i;
            const size_t n = (size_t)rowBase + row;
            unsigned long long bs = bestS[row];
            const int bestk = (bs != ~0ULL) ? (int)(bs & 1023ULL) : kminS[row];

            const float4* q4p = (const float4*)(cbL + (size_t)bestk * DIMD);
            float4 qa = q4p[2 * li], qb = q4p[2 * li + 1];
            float4 ra = rS4[row * 33 + 2 * li], rb = rS4[row * 33 + 2 * li + 1];

            float nr0 = ra.x - qa.x, nr1 = ra.y - qa.y;
            float nr2 = ra.z - qa.z, nr3 = ra.w - qa.w;
            float nr4 = rb.x - qb.x, nr5 = rb.y - qb.y;
            float nr6 = rb.z - qb.z, nr7 = rb.w - qb.w;

            double cpart = 0.0;
            cpart += (double)(nr0 * nr0); cpart += (double)(nr1 * nr1);
            cpart += (double)(nr2 * nr2); cpart += (double)(nr3 * nr3);
            cpart += (double)(nr4 * nr4); cpart += (double)(nr5 * nr5);
            cpart += (double)(nr6 * nr6); cpart += (double)(nr7 * nr7);
            #pragma unroll
            for (int m = 8; m >= 1; m >>= 1) cpart += __shfl_xor(cpart, m);

            rS4[row * 33 + 2 * li]     = make_float4(nr0, nr1, nr2, nr3);
            rS4[row * 33 + 2 * li + 1] = make_float4(nr4, nr5, nr6, nr7);

            if (li == 0) {
                out[(size_t)NROWS * DIMD + n * NLEV + lev] = (float)bestk;
                commitS[row] += (float)cpart;
                usageS[row]  += swS[row] / (1024.0f + devS[row])
                              - log1pf(devS[row] * (1.0f / 1024.0f));
            }
            if (lev == NLEV - 1) {
                float4 xa = x4[n * 32 + 2 * li];
                float4 xb = x4[n * 32 + 2 * li + 1];
                out4[n * 32 + 2 * li] = make_float4(
                    xa.x - nr0, xa.y - nr1, xa.z - nr2, xa.w - nr3);
                out4[n * 32 + 2 * li + 1] = make_float4(
                    xb.x - nr4, xb.y - nr5, xb.z - nr6, xb.w - nr7);
            }
        }
    }

    __syncthreads();
    float u = 0.f, cm = 0.f;
    if (tid < RB) { u = usageS[tid]; cm = commitS[tid]; }
    #pragma unroll
    for (int m = 32; m >= 1; m >>= 1) { u += __shfl_xor(u, m); cm += __shfl_xor(cm, m); }
    if (tid == 0) {
        atomicAdd(&lossAcc[0], (double)cm);
        atomicAdd(&lossAcc[1], (double)u);
    }
}

// prep: loss reset, C = np_sumsq (ref-exact), bf16 hi/lo frag tables (pre-scaled x2)
__global__ void rvq_prep(const float* __restrict__ cb, float* __restrict__ e2g,
                         uint4* __restrict__ hiT, uint4* __restrict__ loT,
                         double* __restrict__ lossAcc)
{
    int idx = blockIdx.x * 256 + threadIdx.x;      // 0..65535
    if (idx == 0) { lossAcc[0] = 0.0; lossAcc[1] = 0.0; }
    if (idx < NLEV * KCB)
        e2g[idx] = np_sumsq128(cb + (size_t)idx * DIMD);

    int lev = idx >> 14, rem = idx & 16383;
    int cg = rem >> 8, ks = (rem >> 6) & 3, lane = rem & 63;
    int col = cg * 16 + (lane & 15);
    int k0  = ks * 32 + (lane >> 4) * 8;
    const float* src = cb + ((size_t)lev * KCB + col) * DIMD + k0;
    unsigned hb[8], lb[8];
    #pragma unroll
    for (int e = 0; e < 8; ++e) {
        float w = 2.0f * src[e];                   // exact scale
        unsigned b = __float_as_uint(w);
        hb[e] = b >> 16;                           // trunc bf16 of 2e
        float lv = w - __uint_as_float(b & 0xFFFF0000u);   // exact
        lb[e] = __float_as_uint(lv) >> 16;         // trunc bf16 of residual
    }
    uint4 hp, lp;
    hp.x = hb[0] | (hb[1] << 16); hp.y = hb[2] | (hb[3] << 16);
    hp.z = hb[4] | (hb[5] << 16); hp.w = hb[6] | (hb[7] << 16);
    lp.x = lb[0] | (lb[1] << 16); lp.y = lb[2] | (lb[3] << 16);
    lp.z = lb[4] | (lb[5] << 16); lp.w = lb[6] | (lb[7] << 16);
    hiT[idx] = hp;
    loT[idx] = lp;
}

__global__ void rvq_fin(const double* __restrict__ lossAcc, float* __restrict__ out)
{
    out[(size_t)NROWS * DIMD + (size_t)NROWS * NLEV] =
        (float)(lossAcc[0] * (1.25 / ((double)NROWS * (double)DIMD)));
    out[(size_t)NROWS * DIMD + (size_t)NROWS * NLEV + 1] =
        (float)(lossAcc[1] / (double)NROWS);
}

extern "C" void kernel_launch(void* const* d_in, const int* in_sizes, int n_in,
                              void* d_out, int out_size, void* d_ws, size_t ws_size,
                              hipStream_t stream)
{
    const float* x  = (const float*)d_in[0];
    const float* cb = (const float*)d_in[1];
    float* out = (float*)d_out;
    double* lossAcc = (double*)d_ws;
    float* e2g = (float*)((char*)d_ws + WS_E2G);
    uint4* hiT = (uint4*)((char*)d_ws + WS_HIT);
    uint4* loT = (uint4*)((char*)d_ws + WS_LOT);

    rvq_prep<<<dim3(256), dim3(256), 0, stream>>>(cb, e2g, hiT, loT, lossAcc);
    rvq_main<<<dim3(NROWS / RB), dim3(64), 0, stream>>>(x, cb, out, e2g, hiT, loT, lossAcc);
    rvq_fin<<<dim3(1), dim3(1), 0, stream>>>(lossAcc, out);
}

// Round 18
// 1061.340 us; speedup vs baseline: 1.5304x; 1.5304x over previous
//
#include <hip/hip_runtime.h>
#include <math.h>

#define NROWS 131072
#define DIMD  128
#define KCB   1024
#define NLEV  4
#define RB    32                 // rows per block (1 wave)
#define EPS_GAP 5.0e-5f          // > 2*delta_max (grid 1.5e-5 + split/chain ~6e-6)

typedef __attribute__((ext_vector_type(8))) short short8;
typedef __attribute__((ext_vector_type(4))) float f32x4;

// d_ws layout (~2.1 MB): [0,16) lossAcc, [16,16400) e2g[4096], hiT/loT frag tables
#define WS_E2G   16
#define WS_HIT   16400
#define WS_LOT   (16400 + 1048576)

// numpy pairwise sumsq (AVX512 path) — validated R3..R17. Do not reassociate.
__device__ __forceinline__ float np_sumsq128(const float* __restrict__ p) {
    float q[16];
    #pragma unroll
    for (int lane = 0; lane < 16; ++lane) {
        float c[8];
        #pragma unroll
        for (int j = 0; j < 8; ++j) { float v = p[16 * j + lane]; c[j] = v * v; }
        float s01 = c[0] + c[1], s23 = c[2] + c[3];
        float s45 = c[4] + c[5], s67 = c[6] + c[7];
        q[lane] = (s01 + s23) + (s45 + s67);
    }
    float t[8];
    #pragma unroll
    for (int j = 0; j < 8; ++j) t[j] = q[j] + q[j + 8];
    float u[4];
    #pragma unroll
    for (int j = 0; j < 4; ++j) u[j] = t[j] + t[j + 4];
    float w0 = u[0] + u[2], w1 = u[1] + u[3];
    return w0 + w1;
}

__device__ __forceinline__ short8 as_short8(uint4 u) {
    short8 v; __builtin_memcpy(&v, &u, 16); return v;
}

// (64,2): keep the R16 occupancy point — 2 waves/SIMD with 128-reg target.
// R17 proved (64,1) halves residency (21.4% -> 11.4%) and loses 500us.
__global__ __launch_bounds__(64, 2)
void rvq_main(const float* __restrict__ x, const float* __restrict__ cb,
              float* __restrict__ out, const float* __restrict__ e2g,
              const uint4* __restrict__ hiT, const uint4* __restrict__ loT,
              double* __restrict__ lossAcc)
{
    __shared__ float rS[RB * 132];                 // f32 residual chain
    __shared__ unsigned long long bestS[RB];
    __shared__ float A_S[RB];
    __shared__ int   kminS[RB], k2S[RB];
    __shared__ float devS[RB], swS[RB];
    __shared__ float commitS[RB], usageS[RB];
    __shared__ int   pairList[RB], fullList[RB];
    __shared__ int   pairCnt, fullCnt;

    const int tid = threadIdx.x;                   // 0..63 (one wave)
    const int li  = tid & 15;
    const int lg  = tid >> 4;
    const int rowBase = blockIdx.x * RB;
    const int cgOff = (int)(blockIdx.x & 63);      // per-block sweep stagger

    float4* rS4 = (float4*)rS;
    const float4* x4 = (const float4*)x;
    float4* out4 = (float4*)out;

    #pragma unroll
    for (int i = 0; i < 8; ++i) {
        int row = 8 * lg + i;
        size_t n = (size_t)rowBase + row;
        rS4[row * 33 + 2 * li]     = x4[n * 32 + 2 * li];
        rS4[row * 33 + 2 * li + 1] = x4[n * 32 + 2 * li + 1];
    }
    if (tid < RB) { commitS[tid] = 0.0f; usageS[tid] = 0.0f; }

    for (int lev = 0; lev < NLEV; ++lev) {
        __syncthreads();
        if (tid < RB) {
            A_S[tid]  = np_sumsq128(rS + tid * 132);
            bestS[tid] = ~0ULL;
        }
        if (tid == 0) { pairCnt = 0; fullCnt = 0; }

        const float* cbL  = cb  + (size_t)lev * KCB * DIMD;
        const float* e2gL = e2g + (size_t)lev * KCB;
        const uint4* hT = hiT + (size_t)lev * 16384;
        const uint4* lT = loT + (size_t)lev * 16384;

        // A fragments (bf16 hi/lo of 32 rows)
        short8 aH[2][4], aL[2][4];
        #pragma unroll
        for (int t = 0; t < 2; ++t) {
            int arow = 16 * t + li;
            #pragma unroll
            for (int ks = 0; ks < 4; ++ks) {
                float4 p = rS4[arow * 33 + 8 * ks + 2 * lg];
                float4 q = rS4[arow * 33 + 8 * ks + 2 * lg + 1];
                uint4 uh, ul;
                float pv[8] = {p.x, p.y, p.z, p.w, q.x, q.y, q.z, q.w};
                unsigned hb[8]; float lv[8];
                #pragma unroll
                for (int e = 0; e < 8; ++e) {
                    unsigned b = __float_as_uint(pv[e]);
                    hb[e] = b & 0xFFFF0000u;
                    lv[e] = pv[e] - __uint_as_float(hb[e]);
                }
                uh.x = (hb[0] >> 16) | hb[1]; uh.y = (hb[2] >> 16) | hb[3];
                uh.z = (hb[4] >> 16) | hb[5]; uh.w = (hb[6] >> 16) | hb[7];
                ul.x = (__float_as_uint(lv[0]) >> 16) | (__float_as_uint(lv[1]) & 0xFFFF0000u);
                ul.y = (__float_as_uint(lv[2]) >> 16) | (__float_as_uint(lv[3]) & 0xFFFF0000u);
                ul.z = (__float_as_uint(lv[4]) >> 16) | (__float_as_uint(lv[5]) & 0xFFFF0000u);
                ul.w = (__float_as_uint(lv[6]) >> 16) | (__float_as_uint(lv[7]) & 0xFFFF0000u);
                aH[t][ks] = as_short8(uh);
                aL[t][ks] = as_short8(ul);
            }
        }

        // top-3 values + top-2 indices per row-slot
        float m1[8], m2[8], m3[8], dev[8], swv[8];
        int   k1[8], k2[8];
        #pragma unroll
        for (int s = 0; s < 8; ++s) {
            m1[s] = -__builtin_inff(); m2[s] = -__builtin_inff(); m3[s] = -__builtin_inff();
            k1[s] = 0; k2[s] = 0; dev[s] = 0.f; swv[s] = 0.f;
        }

        // per-cg compute; Cc prefetched by caller; merged cross-term chains
        // (accM = mfma(aL,bH, mfma(aH,bL, accM))): 4 chains, -8 acc regs.
        auto compute_cg = [&](const uint4 (&hf)[4], const uint4 (&lf)[4],
                              int cgPhys, float Cc) {
            short8 bH[4], bL[4];
            #pragma unroll
            for (int ks = 0; ks < 4; ++ks) { bH[ks] = as_short8(hf[ks]); bL[ks] = as_short8(lf[ks]); }
            f32x4 accH0 = {-Cc,-Cc,-Cc,-Cc}, accH1 = {-Cc,-Cc,-Cc,-Cc};
            f32x4 accM0 = {0.f,0.f,0.f,0.f}, accM1 = {0.f,0.f,0.f,0.f};
            #pragma unroll
            for (int ks = 0; ks < 4; ++ks) {
                accH0 = __builtin_amdgcn_mfma_f32_16x16x32_bf16(aH[0][ks], bH[ks], accH0, 0, 0, 0);
                accH1 = __builtin_amdgcn_mfma_f32_16x16x32_bf16(aH[1][ks], bH[ks], accH1, 0, 0, 0);
                accM0 = __builtin_amdgcn_mfma_f32_16x16x32_bf16(aH[0][ks], bL[ks], accM0, 0, 0, 0);
                accM1 = __builtin_amdgcn_mfma_f32_16x16x32_bf16(aH[1][ks], bL[ks], accM1, 0, 0, 0);
                accM0 = __builtin_amdgcn_mfma_f32_16x16x32_bf16(aL[0][ks], bH[ks], accM0, 0, 0, 0);
                accM1 = __builtin_amdgcn_mfma_f32_16x16x32_bf16(aL[1][ks], bH[ks], accM1, 0, 0, 0);
            }
            const int colg = cgPhys * 16 + li;
            #pragma unroll
            for (int t = 0; t < 2; ++t) {
                #pragma unroll
                for (int r = 0; r < 4; ++r) {
                    const int s = 4 * t + r;
                    float sv = t ? (accH1[r] + accM1[r]) : (accH0[r] + accM0[r]);
                    bool gt1 = sv > m1[s];
                    k2[s] = gt1 ? k1[s] : ((sv > m2[s]) ? colg : k2[s]);
                    k1[s] = gt1 ? colg : k1[s];
                    m3[s] = __builtin_amdgcn_fmed3f(sv, m2[s], m3[s]);   // new 3rd
                    m2[s] = __builtin_amdgcn_fmed3f(sv, m1[s], m2[s]);   // new 2nd
                    m1[s] = fmaxf(sv, m1[s]);
                    float e = __expf(sv);                     // |sv|<~0.35
                    dev[s] += (e - 1.0f);                     // Sterbenz-exact
                    swv[s]  = fmaf(sv, e, swv[s]);
                }
            }
        };

        // sweep 64 staggered col-groups; 2-deep reg double-buffer + Cc prefetch
        uint4 h0[4], l0[4], h1[4], l1[4];
        float c0, c1;
        {
            const int p0 = cgOff;
            #pragma unroll
            for (int ks = 0; ks < 4; ++ks) {
                h0[ks] = hT[(size_t)p0 * 256 + ks * 64 + tid];
                l0[ks] = lT[(size_t)p0 * 256 + ks * 64 + tid];
            }
            c0 = e2gL[p0 * 16 + li];
        }
        for (int g = 0; g < 64; g += 2) {
            const int p1 = (g + 1 + cgOff) & 63;
            #pragma unroll
            for (int ks = 0; ks < 4; ++ks) {
                h1[ks] = hT[(size_t)p1 * 256 + ks * 64 + tid];
                l1[ks] = lT[(size_t)p1 * 256 + ks * 64 + tid];
            }
            c1 = e2gL[p1 * 16 + li];
            compute_cg(h0, l0, (g + cgOff) & 63, c0);
            if (g + 2 < 64) {
                const int p2 = (g + 2 + cgOff) & 63;
                #pragma unroll
                for (int ks = 0; ks < 4; ++ks) {
                    h0[ks] = hT[(size_t)p2 * 256 + ks * 64 + tid];
                    l0[ks] = lT[(size_t)p2 * 256 + ks * 64 + tid];
                }
                c0 = e2gL[p2 * 16 + li];
            }
            compute_cg(h1, l1, p1, c1);
        }

        // merge sorted triples (+indices) across the 16 lanes sharing rows
        #pragma unroll
        for (int s = 0; s < 8; ++s) {
            #pragma unroll
            for (int m = 8; m >= 1; m >>= 1) {
                float b1 = __shfl_xor(m1[s], m), b2 = __shfl_xor(m2[s], m), b3 = __shfl_xor(m3[s], m);
                int  bk1 = __shfl_xor(k1[s], m), bk2 = __shfl_xor(k2[s], m);
                float a1 = m1[s], a2 = m2[s], a3 = m3[s];
                int  ak1 = k1[s], ak2 = k2[s];
                float n1, n2, n3; int nk1, nk2;
                if (a1 > b1) {
                    n1 = a1; nk1 = ak1;
                    if (a2 > b1)      { n2 = a2; nk2 = ak2; n3 = fmaxf(a3, b1); }
                    else if (a2 < b1) { n2 = b1; nk2 = bk1; n3 = fmaxf(a2, b2); }
                    else              { n2 = a2; nk2 = min(ak2, bk1); n3 = a2; }
                } else if (a1 < b1) {
                    n1 = b1; nk1 = bk1;
                    if (b2 > a1)      { n2 = b2; nk2 = bk2; n3 = fmaxf(b3, a1); }
                    else if (b2 < a1) { n2 = a1; nk2 = ak1; n3 = fmaxf(b2, a2); }
                    else              { n2 = b2; nk2 = min(bk2, ak1); n3 = b2; }
                } else {               // value tie at top: both indices kept
                    n1 = a1; nk1 = min(ak1, bk1);
                    n2 = a1; nk2 = (ak1 < bk1) ? bk1 : ak1;
                    n3 = fmaxf(a2, b2);
                }
                m1[s] = n1; m2[s] = n2; m3[s] = n3; k1[s] = nk1; k2[s] = nk2;
                dev[s] += __shfl_xor(dev[s], m);
                swv[s] += __shfl_xor(swv[s], m);
            }
        }

        // owners classify: accept / pair-check / full-scan
        if (li == 0) {
            #pragma unroll
            for (int t = 0; t < 2; ++t)
                #pragma unroll
                for (int r = 0; r < 4; ++r) {
                    const int s = 4 * t + r;
                    const int row = 16 * t + 4 * lg + r;
                    kminS[row] = k1[s];
                    k2S[row]   = k2[s];
                    devS[row]  = dev[s];
                    swS[row]   = swv[s];
                    if (!(m1[s] - m2[s] > EPS_GAP)) {
                        if (m1[s] - m3[s] > EPS_GAP)
                            pairList[atomicAdd(&pairCnt, 1)] = row;   // only k1,k2 contend
                        else
                            fullList[atomicAdd(&fullCnt, 1)] = row;   // ultra-rare
                    }
                }
        }
        __syncthreads();

        // pair rows: exact fp32-replica d32 for k1 (lanes<32) and k2 (lanes>=32)
        const int np = pairCnt;
        for (int h = 0; h < np; ++h) {
            const int row = pairList[h];
            const int myk = (tid < 32) ? kminS[row] : k2S[row];
            const float4* rr4 = (const float4*)(rS + row * 132);
            const float4* ep4 = (const float4*)(cbL + (size_t)myk * DIMD);
            float b = 0.f;
            #pragma unroll 8
            for (int c4 = 0; c4 < 32; ++c4) {      // sequential ascending-d FMA
                float4 rv = rr4[c4], ev = ep4[c4];
                b = fmaf(rv.x, ev.x, b);
                b = fmaf(rv.y, ev.y, b);
                b = fmaf(rv.z, ev.z, b);
                b = fmaf(rv.w, ev.w, b);
            }
            float m2b = 2.0f * b;
            float t1  = A_S[row] - m2b;
            float d32 = t1 + e2gL[myk];
            unsigned long long pk =
                ((unsigned long long)__float_as_uint(d32) << 32) | (unsigned)myk;
            unsigned long long o = __shfl_xor(pk, 32);
            if (o < pk) pk = o;
            if (tid == 0) bestS[row] = pk;
        }

        // full-scan rows (P ~ 3e-5): exact replica over all 1024 k
        const int nf = fullCnt;
        for (int h = 0; h < nf; ++h) {
            const int row = fullList[h];
            const float4* rrow4 = (const float4*)(rS + row * 132);
            const float Ar = A_S[row];
            unsigned long long best = ~0ULL;
            for (int kk = tid; kk < KCB; kk += 64) {
                const float4* ep4 = (const float4*)(cbL + (size_t)kk * DIMD);
                float b = 0.f;
                #pragma unroll 8
                for (int c4 = 0; c4 < 32; ++c4) {
                    float4 ev = ep4[c4];
                    float4 rv = rrow4[c4];
                    b = fmaf(rv.x, ev.x, b);
                    b = fmaf(rv.y, ev.y, b);
                    b = fmaf(rv.z, ev.z, b);
                    b = fmaf(rv.w, ev.w, b);
                }
                float m2b = 2.0f * b;
                float t1  = Ar - m2b;
                float d32 = t1 + e2gL[kk];
                unsigned long long pk =
                    ((unsigned long long)__float_as_uint(d32) << 32) | (unsigned)kk;
                if (pk < best) best = pk;
            }
            #pragma unroll
            for (int m = 32; m >= 1; m >>= 1) {
                unsigned long long o = __shfl_xor(best, m);
                if (o < best) best = o;
            }
            if (tid == 0) bestS[row] = best;
        }
        __syncthreads();

        // epilogue (R3/R6/R14 validated): residual chain, codes, losses, out
        #pragma unroll
        for (int i = 0; i < 8; ++i) {
            const int row = 8 * lg + i;
            const size_t n = (size_t)rowBase + row;
            unsigned long long bs = bestS[row];
            const int bestk = (bs != ~0ULL) ? (int)(bs & 1023ULL) : kminS[row];

            const float4* q4p = (const float4*)(cbL + (size_t)bestk * DIMD);
            float4 qa = q4p[2 * li], qb = q4p[2 * li + 1];
            float4 ra = rS4[row * 33 + 2 * li], rb = rS4[row * 33 + 2 * li + 1];

            float nr0 = ra.x - qa.x, nr1 = ra.y - qa.y;
            float nr2 = ra.z - qa.z, nr3 = ra.w - qa.w;
            float nr4 = rb.x - qb.x, nr5 = rb.y - qb.y;
            float nr6 = rb.z - qb.z, nr7 = rb.w - qb.w;

            double cpart = 0.0;
            cpart += (double)(nr0 * nr0); cpart += (double)(nr1 * nr1);
            cpart += (double)(nr2 * nr2); cpart += (double)(nr3 * nr3);
            cpart += (double)(nr4 * nr4); cpart += (double)(nr5 * nr5);
            cpart += (double)(nr6 * nr6); cpart += (double)(nr7 * nr7);
            #pragma unroll
            for (int m = 8; m >= 1; m >>= 1) cpart += __shfl_xor(cpart, m);

            rS4[row * 33 + 2 * li]     = make_float4(nr0, nr1, nr2, nr3);
            rS4[row * 33 + 2 * li + 1] = make_float4(nr4, nr5, nr6, nr7);

            if (li == 0) {
                out[(size_t)NROWS * DIMD + n * NLEV + lev] = (float)bestk;
                commitS[row] += (float)cpart;
                usageS[row]  += swS[row] / (1024.0f + devS[row])
                              - log1pf(devS[row] * (1.0f / 1024.0f));
            }
            if (lev == NLEV - 1) {
                float4 xa = x4[n * 32 + 2 * li];
                float4 xb = x4[n * 32 + 2 * li + 1];
                out4[n * 32 + 2 * li] = make_float4(
                    xa.x - nr0, xa.y - nr1, xa.z - nr2, xa.w - nr3);
                out4[n * 32 + 2 * li + 1] = make_float4(
                    xb.x - nr4, xb.y - nr5, xb.z - nr6, xb.w - nr7);
            }
        }
    }

    __syncthreads();
    float u = 0.f, cm = 0.f;
    if (tid < RB) { u = usageS[tid]; cm = commitS[tid]; }
    #pragma unroll
    for (int m = 32; m >= 1; m >>= 1) { u += __shfl_xor(u, m); cm += __shfl_xor(cm, m); }
    if (tid == 0) {
        atomicAdd(&lossAcc[0], (double)cm);
        atomicAdd(&lossAcc[1], (double)u);
    }
}

// prep: loss reset, C = np_sumsq (ref-exact), bf16 hi/lo frag tables (pre-scaled x2)
__global__ void rvq_prep(const float* __restrict__ cb, float* __restrict__ e2g,
                         uint4* __restrict__ hiT, uint4* __restrict__ loT,
                         double* __restrict__ lossAcc)
{
    int idx = blockIdx.x * 256 + threadIdx.x;      // 0..65535
    if (idx == 0) { lossAcc[0] = 0.0; lossAcc[1] = 0.0; }
    if (idx < NLEV * KCB)
        e2g[idx] = np_sumsq128(cb + (size_t)idx * DIMD);

    int lev = idx >> 14, rem = idx & 16383;
    int cg = rem >> 8, ks = (rem >> 6) & 3, lane = rem & 63;
    int col = cg * 16 + (lane & 15);
    int k0  = ks * 32 + (lane >> 4) * 8;
    const float* src = cb + ((size_t)lev * KCB + col) * DIMD + k0;
    unsigned hb[8], lb[8];
    #pragma unroll
    for (int e = 0; e < 8; ++e) {
        float w = 2.0f * src[e];                   // exact scale
        unsigned b = __float_as_uint(w);
        hb[e] = b >> 16;                           // trunc bf16 of 2e
        float lv = w - __uint_as_float(b & 0xFFFF0000u);   // exact
        lb[e] = __float_as_uint(lv) >> 16;         // trunc bf16 of residual
    }
    uint4 hp, lp;
    hp.x = hb[0] | (hb[1] << 16); hp.y = hb[2] | (hb[3] << 16);
    hp.z = hb[4] | (hb[5] << 16); hp.w = hb[6] | (hb[7] << 16);
    lp.x = lb[0] | (lb[1] << 16); lp.y = lb[2] | (lb[3] << 16);
    lp.z = lb[4] | (lb[5] << 16); lp.w = lb[6] | (lb[7] << 16);
    hiT[idx] = hp;
    loT[idx] = lp;
}

__global__ void rvq_fin(const double* __restrict__ lossAcc, float* __restrict__ out)
{
    out[(size_t)NROWS * DIMD + (size_t)NROWS * NLEV] =
        (float)(lossAcc[0] * (1.25 / ((double)NROWS * (double)DIMD)));
    out[(size_t)NROWS * DIMD + (size_t)NROWS * NLEV + 1] =
        (float)(lossAcc[1] / (double)NROWS);
}

extern "C" void kernel_launch(void* const* d_in, const int* in_sizes, int n_in,
                              void* d_out, int out_size, void* d_ws, size_t ws_size,
                              hipStream_t stream)
{
    const float* x  = (const float*)d_in[0];
    const float* cb = (const float*)d_in[1];
    float* out = (float*)d_out;
    double* lossAcc = (double*)d_ws;
    float* e2g = (float*)((char*)d_ws + WS_E2G);
    uint4* hiT = (uint4*)((char*)d_ws + WS_HIT);
    uint4* loT = (uint4*)((char*)d_ws + WS_LOT);

    rvq_prep<<<dim3(256), dim3(256), 0, stream>>>(cb, e2g, hiT, loT, lossAcc);
    rvq_main<<<dim3(NROWS / RB), dim3(64), 0, stream>>>(x, cb, out, e2g, hiT, loT, lossAcc);
    rvq_fin<<<dim3(1), dim3(1), 0, stream>>>(lossAcc, out);
}